// Round 12
// baseline (184.683 us; speedup 1.0000x reference)
//
#include <hip/hip_runtime.h>

#define DEVINL __device__ __forceinline__

// 3-level a-trous B3-spline UWT, fused single kernel.
// REVERT to the measured-best STRIDED structure (16.1 us kernel; the
// rolling-window and pair/quad tap-sharing variants both regressed to
// ~20-21 us: body-widening hurt codegen more than the -37% LDS traffic
// helped — kernel is a mixed VALU+LDS bound, neither pipe dominant).
// ONE isolated change vs the 179.11-baseline: per-store 64-bit address
// chain hoisted to a per-thread obase (stores become base + const + shift).
//
// Tile: 32x64 output, staged 64x92 rows (2..93), SW padded to 68 floats.
// pack p = tid&15 owns 4 cols (float4); ty = tid>>4 walks rows stride 16.
// Per level: vertical 5-tap via 5 independent ds_read_b128 (compile-time
// offsets, good MLP), horizontal 5-tap via DPP row_shr/row_shl.
// LDS ping-pong A<->B, 2 x 96 x 68 x 4 = 52.2 KB -> 3 blocks/CU.

constexpr int W_IMG = 1024;
constexpr int H_IMG = 1024;
constexpr int TX = 32;                    // output cols per tile
constexpr int TY = 64;                    // output rows per tile (GYT exact)
constexpr int HALO = 16;                  // >= 2*(1+2+4)=14
constexpr int SW = 68;                    // LDS row STRIDE in floats (64 + 4 pad)
constexpr int SH = 96;                    // row slots (2..93 staged)
constexpr int GXT = W_IMG / TX;           // 32
constexpr int GYT = H_IMG / TY;           // 16 (exact)

constexpr float TP0 = 1.0f / 16.0f;
constexpr float TP1 = 1.0f / 4.0f;
constexpr float TP2 = 3.0f / 8.0f;

typedef float f32x4 __attribute__((ext_vector_type(4)));

// DPP cross-lane fetch within 16-lane rows. row_shr:n (0x110|n) = value from
// lane i-n; row_shl:n (0x100|n) = value from lane i+n. bound_ctrl=1 -> 0 at
// row edges. Corruption chain: L0 -> staged cols {0,1},{62,63}; L1 ->
// {0..5},{58..63}; L2 -> {0..13},{50..63}. Outputs use cols 16..47 (margin 2).
template <int CTRL>
DEVINL float dppf(float x) {
    return __int_as_float(__builtin_amdgcn_update_dpp(
        0, __float_as_int(x), CTRL, 0xF, 0xF, true));
}

DEVINL int reflx(int g) {
    g = g < 0 ? -g : g;
    return g >= W_IMG ? 2 * W_IMG - 2 - g : g;
}

DEVINL void nt_store4(float* p, float a, float b, float c, float d) {
    f32x4 t;
    t.x = a; t.y = b; t.z = c; t.w = d;
    __builtin_nontemporal_store(t, (f32x4*)p);
}

DEVINL float4 ld4(const float* p) { return *(const float4*)p; }

DEVINL float4 vert(const float4& a0, const float4& a1, const float4& a2,
                   const float4& a3, const float4& a4) {
    float4 v;
    v.x = TP0 * (a0.x + a4.x) + TP1 * (a1.x + a3.x) + TP2 * a2.x;
    v.y = TP0 * (a0.y + a4.y) + TP1 * (a1.y + a3.y) + TP2 * a2.y;
    v.z = TP0 * (a0.z + a4.z) + TP1 * (a1.z + a3.z) + TP2 * a2.z;
    v.w = TP0 * (a0.w + a4.w) + TP1 * (a1.w + a3.w) + TP2 * a2.w;
    return v;
}

template <int D>
DEVINL float4 horiz(const float4& v) {
    float4 u;
    if constexpr (D == 1) {
        const float am2 = dppf<0x111>(v.z);  // col-2 for comp0
        const float am1 = dppf<0x111>(v.w);  // col-1 for comp0
        const float ap1 = dppf<0x101>(v.x);  // col+1 for comp3
        const float ap2 = dppf<0x101>(v.y);  // col+2 for comp3
        u.x = TP0 * (am2 + v.z) + TP1 * (am1 + v.y) + TP2 * v.x;
        u.y = TP0 * (am1 + v.w) + TP1 * (v.x + v.z) + TP2 * v.y;
        u.z = TP0 * (v.x + ap1) + TP1 * (v.y + v.w) + TP2 * v.z;
        u.w = TP0 * (v.y + ap2) + TP1 * (v.z + ap1) + TP2 * v.w;
    } else if constexpr (D == 2) {
        u.x = TP0 * (dppf<0x111>(v.x) + dppf<0x101>(v.x)) +
              TP1 * (dppf<0x111>(v.z) + v.z) + TP2 * v.x;
        u.y = TP0 * (dppf<0x111>(v.y) + dppf<0x101>(v.y)) +
              TP1 * (dppf<0x111>(v.w) + v.w) + TP2 * v.y;
        u.z = TP0 * (dppf<0x111>(v.z) + dppf<0x101>(v.z)) +
              TP1 * (v.x + dppf<0x101>(v.x)) + TP2 * v.z;
        u.w = TP0 * (dppf<0x111>(v.w) + dppf<0x101>(v.w)) +
              TP1 * (v.y + dppf<0x101>(v.y)) + TP2 * v.w;
    } else {  // D == 4: same component, packs +/-1 and +/-2
        u.x = TP0 * (dppf<0x112>(v.x) + dppf<0x102>(v.x)) +
              TP1 * (dppf<0x111>(v.x) + dppf<0x101>(v.x)) + TP2 * v.x;
        u.y = TP0 * (dppf<0x112>(v.y) + dppf<0x102>(v.y)) +
              TP1 * (dppf<0x111>(v.y) + dppf<0x101>(v.y)) + TP2 * v.y;
        u.z = TP0 * (dppf<0x112>(v.z) + dppf<0x102>(v.z)) +
              TP1 * (dppf<0x111>(v.z) + dppf<0x101>(v.z)) + TP2 * v.z;
        u.w = TP0 * (dppf<0x112>(v.w) + dppf<0x102>(v.w)) +
              TP1 * (dppf<0x111>(v.w) + dppf<0x101>(v.w)) + TP2 * v.w;
    }
    return u;
}

// Strided level: each 16-lane row-group owns rows R0+ty, stride 16, r<R1.
// 5 independent ds_read_b128 per row (slim body — the codegen sweet spot).
// Stores via hoisted obase: addr = obase + LVL*PL + (ly<<10).
template <int D, int R0, int R1, int LVL, bool LAST>
DEVINL void do_level(const float* src, float* dst, float* obase, bool pok,
                     int ty, int c4) {
    constexpr size_t PL = (size_t)H_IMG * W_IMG;
    constexpr int KMAX = (R1 - R0 + 15) / 16;
#pragma unroll 2
    for (int k = 0; k < KMAX; ++k) {
        const int r = R0 + ty + 16 * k;
        if (r < R1) {  // uniform across each 16-lane DPP row (same ty)
            const float* b = &src[r * SW + c4];
            const float4 a0 = ld4(b - 2 * D * SW);
            const float4 a1 = ld4(b - D * SW);
            const float4 a2 = ld4(b);
            const float4 a3 = ld4(b + D * SW);
            const float4 a4 = ld4(b + 2 * D * SW);
            const float4 v = vert(a0, a1, a2, a3, a4);
            const float4 u = horiz<D>(v);
            const int ly = r - HALO;
            if (pok && (unsigned)ly < (unsigned)TY) {
                float* pw = obase + (size_t)LVL * PL + ((size_t)ly << 10);
                nt_store4(pw, a2.x - u.x, a2.y - u.y, a2.z - u.z, a2.w - u.w);
                if constexpr (LAST) {
                    float* pc = obase + (size_t)3 * PL + ((size_t)ly << 10);
                    nt_store4(pc, u.x, u.y, u.z, u.w);  // c_3
                }
            }
            if constexpr (!LAST) *(float4*)&dst[r * SW + c4] = u;
        }
    }
}

__global__ __launch_bounds__(256, 3) void uwt3(const float* __restrict__ x,
                                               float* __restrict__ out) {
    __shared__ __align__(16) float A[SH * SW];  // 26112 B
    __shared__ __align__(16) float B[SH * SW];  // total 52224 B -> 3 blk/CU

    const int tid = threadIdx.x;
    const int p = tid & 15;
    const int ty = tid >> 4;
    int bid = blockIdx.x;
    const int bx = bid & 31;  bid >>= 5;      // GXT = 32 (pow2)
    const int by = bid & 15;                  // GYT = 16 (pow2)
    const int b = bid >> 4;
    const int oy0 = by * TY;
    const int gx0 = bx * TX;
    const float* xb = x + (size_t)b * (H_IMG * W_IMG);
    const int c4 = p * 4;
    const bool edge = (bx == 0) || (bx == GXT - 1);
    const bool pok = (p >= 4) && (p < 12);
    // hoisted per-thread output base (deref'd only when pok; oy0+ly<=1023
    // always, so no oy bound check needed)
    float* obase = out + ((size_t)(b * 4) * H_IMG + oy0) * W_IMG +
                   (gx0 + c4 - HALO);

    // stage rows 2..93 only (L0's exact tap reach); 92 rows
#pragma unroll 2
    for (int k = 0; k < 6; ++k) {
        const int sr = 2 + ty + 16 * k;
        if (sr < 94) {
            int gy = oy0 - HALO + sr;
            gy = gy < 0 ? -gy : gy;
            if (gy >= H_IMG) gy = 2 * H_IMG - 2 - gy;
            const float* row = xb + (size_t)gy * W_IMG;
            const int gx = gx0 - HALO + c4;
            float4 v;
            if (!edge) {
                v = *(const float4*)(row + gx);
            } else {
                v.x = row[reflx(gx)];
                v.y = row[reflx(gx + 1)];
                v.z = row[reflx(gx + 2)];
                v.w = row[reflx(gx + 3)];
            }
            *(float4*)&A[sr * SW + c4] = v;
        }
    }
    __syncthreads();

    do_level<1, 4, 92, 0, false>(A, B, obase, pok, ty, c4);  // B rows 4..91
    __syncthreads();
    do_level<2, 8, 88, 1, false>(B, A, obase, pok, ty, c4);  // A rows 8..87
    __syncthreads();
    do_level<4, 16, 80, 2, true>(A, B, obase, pok, ty, c4);
}

extern "C" void kernel_launch(void* const* d_in, const int* in_sizes, int n_in,
                              void* d_out, int out_size, void* d_ws,
                              size_t ws_size, hipStream_t stream) {
    const float* x = (const float*)d_in[0];
    float* out = (float*)d_out;
    const int nb = in_sizes[0] / (H_IMG * W_IMG);  // 8
    dim3 grid(nb * GYT * GXT);                     // 8*16*32 = 4096
    uwt3<<<grid, 256, 0, stream>>>(x, out);
}

// Round 13
// 184.479 us; speedup vs baseline: 1.0011x; 1.0011x over previous
//
#include <hip/hip_runtime.h>

#define DEVINL __device__ __forceinline__

// 3-level a-trous B3-spline UWT, fused single kernel.
// OCCUPANCY PROBE (branch-splitting experiment): same slim strided body as
// the 16.1-us baseline, tile 32x64 -> 32x32. LDS (60+56)x68x4 = 31.5 KB ->
// 4-5 blocks/CU (16-20 waves, vs 12), at +17% conv rows / +30% staged reads.
//   latency-bound  -> predicted dur ~176-178 (win; push occupancy further)
//   throughput-bound -> predicted dur ~182-184 (loss; go cut work: wider
//                       tiles / line-buffer band, not occupancy)
//
// Structure: pack p = tid&15 owns 4 cols (float4); ty = tid>>4 walks rows
// stride 16. Vertical 5-tap via 5 independent ds_read_b128 (compile-time
// offsets, MLP preserved — rolling/pair variants that broke this regressed);
// horizontal 5-tap via DPP row_shr/row_shl within 16-lane rows.
// A holds input rows 2..61 (60 slots, slot = r-2), B holds L0 rows 4..59
// (56 slots, slot = r-4), L1 rows 8..55 reuse A (slot = r-8).

constexpr int W_IMG = 1024;
constexpr int H_IMG = 1024;
constexpr int TX = 32;                    // output cols per tile
constexpr int TY = 32;                    // output rows per tile (GYT exact)
constexpr int HALO = 16;                  // >= 2*(1+2+4)=14
constexpr int SW = 68;                    // LDS row STRIDE in floats (64 + 4 pad)
constexpr int GXT = W_IMG / TX;           // 32
constexpr int GYT = H_IMG / TY;           // 32 (exact)
constexpr int SHA = 60;                   // A slots: input rows 2..61
constexpr int SHB = 56;                   // B slots: L0 rows 4..59

constexpr float TP0 = 1.0f / 16.0f;
constexpr float TP1 = 1.0f / 4.0f;
constexpr float TP2 = 3.0f / 8.0f;

typedef float f32x4 __attribute__((ext_vector_type(4)));

// DPP cross-lane fetch within 16-lane rows. row_shr:n (0x110|n) = value from
// lane i-n; row_shl:n (0x100|n) = value from lane i+n. bound_ctrl=1 -> 0 at
// row edges. Corruption chain: L0 -> staged cols {0,1},{62,63}; L1 ->
// {0..5},{58..63}; L2 -> {0..13},{50..63}. Outputs use cols 16..47 (margin 2).
template <int CTRL>
DEVINL float dppf(float x) {
    return __int_as_float(__builtin_amdgcn_update_dpp(
        0, __float_as_int(x), CTRL, 0xF, 0xF, true));
}

DEVINL int reflx(int g) {
    g = g < 0 ? -g : g;
    return g >= W_IMG ? 2 * W_IMG - 2 - g : g;
}

DEVINL void nt_store4(float* p, float a, float b, float c, float d) {
    f32x4 t;
    t.x = a; t.y = b; t.z = c; t.w = d;
    __builtin_nontemporal_store(t, (f32x4*)p);
}

DEVINL float4 ld4(const float* p) { return *(const float4*)p; }

DEVINL float4 vert(const float4& a0, const float4& a1, const float4& a2,
                   const float4& a3, const float4& a4) {
    float4 v;
    v.x = TP0 * (a0.x + a4.x) + TP1 * (a1.x + a3.x) + TP2 * a2.x;
    v.y = TP0 * (a0.y + a4.y) + TP1 * (a1.y + a3.y) + TP2 * a2.y;
    v.z = TP0 * (a0.z + a4.z) + TP1 * (a1.z + a3.z) + TP2 * a2.z;
    v.w = TP0 * (a0.w + a4.w) + TP1 * (a1.w + a3.w) + TP2 * a2.w;
    return v;
}

template <int D>
DEVINL float4 horiz(const float4& v) {
    float4 u;
    if constexpr (D == 1) {
        const float am2 = dppf<0x111>(v.z);  // col-2 for comp0
        const float am1 = dppf<0x111>(v.w);  // col-1 for comp0
        const float ap1 = dppf<0x101>(v.x);  // col+1 for comp3
        const float ap2 = dppf<0x101>(v.y);  // col+2 for comp3
        u.x = TP0 * (am2 + v.z) + TP1 * (am1 + v.y) + TP2 * v.x;
        u.y = TP0 * (am1 + v.w) + TP1 * (v.x + v.z) + TP2 * v.y;
        u.z = TP0 * (v.x + ap1) + TP1 * (v.y + v.w) + TP2 * v.z;
        u.w = TP0 * (v.y + ap2) + TP1 * (v.z + ap1) + TP2 * v.w;
    } else if constexpr (D == 2) {
        u.x = TP0 * (dppf<0x111>(v.x) + dppf<0x101>(v.x)) +
              TP1 * (dppf<0x111>(v.z) + v.z) + TP2 * v.x;
        u.y = TP0 * (dppf<0x111>(v.y) + dppf<0x101>(v.y)) +
              TP1 * (dppf<0x111>(v.w) + v.w) + TP2 * v.y;
        u.z = TP0 * (dppf<0x111>(v.z) + dppf<0x101>(v.z)) +
              TP1 * (v.x + dppf<0x101>(v.x)) + TP2 * v.z;
        u.w = TP0 * (dppf<0x111>(v.w) + dppf<0x101>(v.w)) +
              TP1 * (v.y + dppf<0x101>(v.y)) + TP2 * v.w;
    } else {  // D == 4: same component, packs +/-1 and +/-2
        u.x = TP0 * (dppf<0x112>(v.x) + dppf<0x102>(v.x)) +
              TP1 * (dppf<0x111>(v.x) + dppf<0x101>(v.x)) + TP2 * v.x;
        u.y = TP0 * (dppf<0x112>(v.y) + dppf<0x102>(v.y)) +
              TP1 * (dppf<0x111>(v.y) + dppf<0x101>(v.y)) + TP2 * v.y;
        u.z = TP0 * (dppf<0x112>(v.z) + dppf<0x102>(v.z)) +
              TP1 * (dppf<0x111>(v.z) + dppf<0x101>(v.z)) + TP2 * v.z;
        u.w = TP0 * (dppf<0x112>(v.w) + dppf<0x102>(v.w)) +
              TP1 * (dppf<0x111>(v.w) + dppf<0x101>(v.w)) + TP2 * v.w;
    }
    return u;
}

// Strided level. src slot = r - SOFF, dst slot = r - DOFF (linear offsets,
// compile-time). 5 independent ds_read_b128 per row (slim body).
template <int D, int R0, int R1, int SOFF, int DOFF, int LVL, bool LAST>
DEVINL void do_level(const float* src, float* dst, float* obase, bool pok,
                     int ty, int c4) {
    constexpr size_t PL = (size_t)H_IMG * W_IMG;
    constexpr int KMAX = (R1 - R0 + 15) / 16;
#pragma unroll 2
    for (int k = 0; k < KMAX; ++k) {
        const int r = R0 + ty + 16 * k;
        if (r < R1) {  // uniform across each 16-lane DPP row (same ty)
            const float* b = &src[(r - SOFF) * SW + c4];
            const float4 a0 = ld4(b - 2 * D * SW);
            const float4 a1 = ld4(b - D * SW);
            const float4 a2 = ld4(b);
            const float4 a3 = ld4(b + D * SW);
            const float4 a4 = ld4(b + 2 * D * SW);
            const float4 v = vert(a0, a1, a2, a3, a4);
            const float4 u = horiz<D>(v);
            const int ly = r - HALO;
            if (pok && (unsigned)ly < (unsigned)TY) {
                float* pw = obase + (size_t)LVL * PL + ((size_t)ly << 10);
                nt_store4(pw, a2.x - u.x, a2.y - u.y, a2.z - u.z, a2.w - u.w);
                if constexpr (LAST) {
                    float* pc = obase + (size_t)3 * PL + ((size_t)ly << 10);
                    nt_store4(pc, u.x, u.y, u.z, u.w);  // c_3
                }
            }
            if constexpr (!LAST) *(float4*)&dst[(r - DOFF) * SW + c4] = u;
        }
    }
}

__global__ __launch_bounds__(256, 4) void uwt3(const float* __restrict__ x,
                                               float* __restrict__ out) {
    __shared__ __align__(16) float A[SHA * SW];  // 16320 B
    __shared__ __align__(16) float B[SHB * SW];  // 15232 B; total 31552 B

    const int tid = threadIdx.x;
    const int p = tid & 15;
    const int ty = tid >> 4;
    int bid = blockIdx.x;
    const int bx = bid & 31;   bid >>= 5;     // GXT = 32 (pow2)
    const int by = bid & 31;                  // GYT = 32 (pow2)
    const int b = bid >> 5;
    const int oy0 = by * TY;
    const int gx0 = bx * TX;
    const float* xb = x + (size_t)b * (H_IMG * W_IMG);
    const int c4 = p * 4;
    const bool edge = (bx == 0) || (bx == GXT - 1);
    const bool pok = (p >= 4) && (p < 12);
    // hoisted per-thread output base (deref'd only when pok; oy0+ly<=1023)
    float* obase = out + ((size_t)(b * 4) * H_IMG + oy0) * W_IMG +
                   (gx0 + c4 - HALO);

    // stage input rows 2..61 (L0's exact tap reach) into A, slot = row-2
#pragma unroll 2
    for (int k = 0; k < 4; ++k) {
        const int sr = 2 + ty + 16 * k;
        if (sr < 62) {
            int gy = oy0 - HALO + sr;
            gy = gy < 0 ? -gy : gy;
            if (gy >= H_IMG) gy = 2 * H_IMG - 2 - gy;
            const float* row = xb + (size_t)gy * W_IMG;
            const int gx = gx0 - HALO + c4;
            float4 v;
            if (!edge) {
                v = *(const float4*)(row + gx);
            } else {
                v.x = row[reflx(gx)];
                v.y = row[reflx(gx + 1)];
                v.z = row[reflx(gx + 2)];
                v.w = row[reflx(gx + 3)];
            }
            *(float4*)&A[(sr - 2) * SW + c4] = v;
        }
    }
    __syncthreads();

    // L0: rows 4..59 -> B (slot r-4); reads A rows 2..61 exactly
    do_level<1, 4, 60, 2, 4, 0, false>(A, B, obase, pok, ty, c4);
    __syncthreads();
    // L1: rows 8..55 -> A (slot r-8); reads B rows 4..59 exactly
    do_level<2, 8, 56, 4, 8, 1, false>(B, A, obase, pok, ty, c4);
    __syncthreads();
    // L2: rows 16..47 (exact output band); reads A(L1) rows 8..55 exactly
    do_level<4, 16, 48, 8, 0, 2, true>(A, B, obase, pok, ty, c4);
}

extern "C" void kernel_launch(void* const* d_in, const int* in_sizes, int n_in,
                              void* d_out, int out_size, void* d_ws,
                              size_t ws_size, hipStream_t stream) {
    const float* x = (const float*)d_in[0];
    float* out = (float*)d_out;
    const int nb = in_sizes[0] / (H_IMG * W_IMG);  // 8
    dim3 grid(nb * GYT * GXT);                     // 8*32*32 = 8192
    uwt3<<<grid, 256, 0, stream>>>(x, out);
}